// Round 9
// baseline (155.053 us; speedup 1.0000x reference)
//
#include <hip/hip_runtime.h>
#include <math.h>

// Sizes fixed by the reference
#define NB 2
#define NN 256
#define KD 16
#define VV 32000
#define EPS_SELF 1e-8f
#define EPS_AL   1e-6f
#define NNODES (NB*NN)   // 512

#define CE_ROWS 8
#define CE_SLOTS 16
// 3-tier vocab chunks: slots 0-3 (prep blocks) 1000; 4-7 (align-only) 2500; 8-15 (exit-only) 2250
// 4*1000 + 4*2500 + 8*2250 = 32000

// ws layout (float offsets)
#define OFF_MT  0                        // 512*16  rotated means mt
#define OFF_O   (NNODES*16)              // 512*256 O = Shat + mt mt^T
#define OFF_P   (OFF_O + NNODES*256)     // 512*256 P = inv(Shat)
#define OFF_LD  (OFF_P + NNODES*256)     // 512     2*sum log(sqrt(d_k)+eps)
#define OFF_KLS (OFF_LD + NNODES)        // 512     per-node kl_self
#define OFF_AP  (OFF_KLS + NNODES)       // 512     align tile partials
#define OFF_Y   (OFF_AP + NNODES)        // 512*16  y = P mt
#define OFF_W   (OFF_Y + NNODES*16)      // 512     w = mt^T P mt
#define OFF_CEP (OFF_W + NNODES)         // 512*16  ce chunk partial sums
#define OFF_CNT (OFF_CEP + NNODES*CE_SLOTS) // 2 uints: prep_cnt, align_cnt
#define WS_FLOATS (OFF_CNT + 4)

// wave-synchronous LDS visibility (DS pipe in-order per wave): drain lgkm.
#define WAVE_SYNC() asm volatile("s_waitcnt lgkmcnt(0)" ::: "memory")

__device__ __forceinline__ void ld4(float* dst, const float4 v) {
  dst[0] = v.x; dst[1] = v.y; dst[2] = v.z; dst[3] = v.w;
}

__device__ __forceinline__ float dot16a(const float* a, const float* b) {
  float acc = 0.f;
  #pragma unroll
  for (int j = 0; j < 16; ++j) acc = fmaf(a[j], b[j], acc);
  return acc;
}

__device__ __forceinline__ float dot4(float4 a, float4 b) {
  return fmaf(a.x, b.x, fmaf(a.y, b.y, fmaf(a.z, b.z, a.w * b.w)));
}

// In-register Gauss-Jordan inverse of 16x16 via shuffles.
__device__ __forceinline__ void gj16(float aq[4], const int g, const int c, float* ldacc) {
  #pragma unroll
  for (int k = 0; k < 16; ++k) {
    float d    = __shfl(aq[k & 3], ((k >> 2) << 4) | k);
    float rowk = __shfl(aq[k & 3], ((k >> 2) << 4) | c);
    float ck[4];
    #pragma unroll
    for (int q = 0; q < 4; ++q) ck[q] = __shfl(aq[q], (g << 4) | k);
    if (ldacc) *ldacc += logf(d);
    float dinv = 1.f / d;
    #pragma unroll
    for (int q = 0; q < 4; ++q) {
      int r = 4*g + q;
      float vgen = fmaf(-ck[q] * dinv, rowk, aq[q]);
      aq[q] = (r == k) ? ((c == k) ? dinv : aq[q] * dinv)
                       : ((c == k) ? (-ck[q] * dinv) : vgen);
    }
  }
}

template<int QUIRK>
__device__ __forceinline__ float ge16_logdet(float aq[4], const int g, const int c) {
  float ld = 0.f;
  #pragma unroll
  for (int k = 0; k < 16; ++k) {
    float d    = __shfl(aq[k & 3], ((k >> 2) << 4) | k);
    float rowk = __shfl(aq[k & 3], ((k >> 2) << 4) | c);
    float ck[4];
    #pragma unroll
    for (int q = 0; q < 4; ++q) ck[q] = __shfl(aq[q], (g << 4) | k);
    ld += QUIRK ? 2.f * logf(sqrtf(d) + EPS_AL) : logf(d);
    float dinv = 1.f / d;
    #pragma unroll
    for (int q = 0; q < 4; ++q) {
      int r = 4*g + q;
      float upd = fmaf(-ck[q] * dinv, rowk, aq[q]);
      aq[q] = (r > k && c > k) ? upd : aq[q];
    }
  }
  return ld;
}

#define PSTR 260

// ---------------- MEGA kernel, 1024 blocks (4/CU co-resident) ----------------
// blocks 0..255:   prep -> CE(slot 0-3, 1000) -> spin -> align tile bid -> maybe final
// blocks 256..511: CE(slot 4-7, 2500) -> spin -> align tile bid -> maybe final
// blocks 512..1023: CE(slot 8-15, 2250) -> release -> maybe final
__global__ __launch_bounds__(256, 4) void mega_kernel(
    const float* __restrict__ mu, const float* __restrict__ Sigma,
    const float* __restrict__ phi, const float* __restrict__ mu_prior,
    const float* __restrict__ Sigma_prior, const float* __restrict__ gen,
    const float* __restrict__ W, const float* __restrict__ beta,
    const int* __restrict__ targets, float* __restrict__ ws,
    float* __restrict__ out)
{
  __shared__ __align__(16) float smem[8896];   // 35.6 KB, unioned across phases
  __shared__ int lastflag;
  const int tid = threadIdx.x;
  const int bid = blockIdx.x;
  unsigned* prep_cnt  = (unsigned*)(ws + OFF_CNT);
  unsigned* align_cnt = prep_cnt + 1;

  // ================= Phase P: prep (blocks 0..255) =================
  if (bid < 256) {
    const int w = tid >> 6, l = tid & 63;
    const int g = l >> 4, c = l & 15;
    const int unit = bid * 4 + w;
    const int role = unit & 1, node = unit >> 1;
    float* COLp = &smem[w*980];
    float* ROWp = COLp + 320;
    float* AUXp = COLp + 640;

    if (role == 0) {
      float phis[16];
      {
        const float4* p4 = (const float4*)(phi + node*16);
        ld4(phis, p4[0]); ld4(phis+4, p4[1]); ld4(phis+8, p4[2]); ld4(phis+12, p4[3]);
      }
      float x[4] = {0.f, 0.f, 0.f, 0.f};
      #pragma unroll
      for (int aa = 0; aa < 16; ++aa) {
        float4 gq = *(const float4*)(gen + aa*256 + c*16 + 4*g);
        x[0] = fmaf(phis[aa], gq.x, x[0]);
        x[1] = fmaf(phis[aa], gq.y, x[1]);
        x[2] = fmaf(phis[aa], gq.z, x[2]);
        x[3] = fmaf(phis[aa], gq.w, x[3]);
      }
      #pragma unroll
      for (int q = 0; q < 4; ++q) x[q] *= -0.125f;

      #pragma unroll
      for (int q = 0; q < 4; ++q) ROWp[(4*g+q)*20 + c] = x[q];
      WAVE_SYNC();
      float Mrow[4][16];
      #pragma unroll
      for (int q = 0; q < 4; ++q)
        #pragma unroll
        for (int j4 = 0; j4 < 4; ++j4)
          ld4(&Mrow[q][4*j4], *(const float4*)&ROWp[(4*g+q)*20 + 4*j4]);

      float t[4];
      #pragma unroll
      for (int q = 0; q < 4; ++q) t[q] = ((4*g+q) == c ? 1.f : 0.f) + x[q]*0.125f;
      for (int k = 7; k >= 1; --k) {
        *(float4*)&COLp[c*20 + 4*g] = make_float4(t[0], t[1], t[2], t[3]);
        WAVE_SYNC();
        float T[16];
        #pragma unroll
        for (int j4 = 0; j4 < 4; ++j4) ld4(&T[4*j4], *(const float4*)&COLp[c*20 + 4*j4]);
        #pragma unroll
        for (int q = 0; q < 4; ++q)
          t[q] = ((4*g+q) == c ? 1.f : 0.f) + dot16a(Mrow[q], T) / (float)k;
      }
      for (int s = 0; s < 3; ++s) {
        *(float4*)&COLp[c*20 + 4*g] = make_float4(t[0], t[1], t[2], t[3]);
        #pragma unroll
        for (int q = 0; q < 4; ++q) ROWp[(4*g+q)*20 + c] = t[q];
        WAVE_SYNC();
        float T[16];
        #pragma unroll
        for (int j4 = 0; j4 < 4; ++j4) ld4(&T[4*j4], *(const float4*)&COLp[c*20 + 4*j4]);
        float nt[4];
        #pragma unroll
        for (int q = 0; q < 4; ++q) {
          float acc = 0.f;
          #pragma unroll
          for (int j4 = 0; j4 < 4; ++j4) {
            float4 rv = *(const float4*)&ROWp[(4*g+q)*20 + 4*j4];
            acc = fmaf(rv.x, T[4*j4+0], acc);
            acc = fmaf(rv.y, T[4*j4+1], acc);
            acc = fmaf(rv.z, T[4*j4+2], acc);
            acc = fmaf(rv.w, T[4*j4+3], acc);
          }
          nt[q] = acc;
        }
        #pragma unroll
        for (int q = 0; q < 4; ++q) t[q] = nt[q];
      }
      *(float4*)&COLp[c*20 + 4*g] = make_float4(t[0], t[1], t[2], t[3]);
      WAVE_SYNC();
      float Ecol[16];
      #pragma unroll
      for (int j4 = 0; j4 < 4; ++j4) ld4(&Ecol[4*j4], *(const float4*)&COLp[c*20 + 4*j4]);

      float w1q[4];
      #pragma unroll
      for (int q = 0; q < 4; ++q) {
        float S[16];
        const float4* s4 = (const float4*)(Sigma + node*256 + (4*g+q)*16);
        ld4(S, s4[0]); ld4(S+4, s4[1]); ld4(S+8, s4[2]); ld4(S+12, s4[3]);
        w1q[q] = dot16a(S, Ecol);
      }
      *(float4*)&AUXp[c*20 + 4*g] = make_float4(w1q[0], w1q[1], w1q[2], w1q[3]);
      WAVE_SYNC();
      float W1c[16];
      #pragma unroll
      for (int j4 = 0; j4 < 4; ++j4) ld4(&W1c[4*j4], *(const float4*)&AUXp[c*20 + 4*j4]);

      float sh[4];
      #pragma unroll
      for (int q = 0; q < 4; ++q) {
        float Er[16];
        #pragma unroll
        for (int j4 = 0; j4 < 4; ++j4) ld4(&Er[4*j4], *(const float4*)&COLp[(4*g+q)*20 + 4*j4]);
        sh[q] = dot16a(Er, W1c) + ((4*g+q) == c ? EPS_AL : 0.f);
      }

      float mtc;
      {
        float muv[16];
        const float4* m4 = (const float4*)(mu + node*16);
        ld4(muv, m4[0]); ld4(muv+4, m4[1]); ld4(muv+8, m4[2]); ld4(muv+12, m4[3]);
        mtc = dot16a(Ecol, muv);
      }
      float mt4[4];
      #pragma unroll
      for (int q = 0; q < 4; ++q) mt4[q] = __shfl(mtc, 4*g + q);

      *(float4*)(ws + OFF_O + node*256 + c*16 + 4*g) =
          make_float4(fmaf(mt4[0], mtc, sh[0]), fmaf(mt4[1], mtc, sh[1]),
                      fmaf(mt4[2], mtc, sh[2]), fmaf(mt4[3], mtc, sh[3]));
      if (g == 0) ws[OFF_MT + node*16 + c] = mtc;

      gj16(sh, g, c, (float*)nullptr);
      *(float4*)(ws + OFF_P + node*256 + c*16 + 4*g) = make_float4(sh[0], sh[1], sh[2], sh[3]);

      float part = sh[0]*mt4[0] + sh[1]*mt4[1] + sh[2]*mt4[2] + sh[3]*mt4[3];
      part += __shfl_xor(part, 16);
      part += __shfl_xor(part, 32);
      if (g == 0) ws[OFF_Y + node*16 + c] = part;
      float wv = mtc * part;
      wv += __shfl_xor(wv, 1); wv += __shfl_xor(wv, 2);
      wv += __shfl_xor(wv, 4); wv += __shfl_xor(wv, 8);
      if (l == 0) ws[OFF_W + node] = wv;
    } else {
      float sp[4];
      {
        float4 v = *(const float4*)(Sigma_prior + node*256 + c*16 + 4*g);
        sp[0] = v.x + ((4*g+0 == c) ? EPS_SELF : 0.f);
        sp[1] = v.y + ((4*g+1 == c) ? EPS_SELF : 0.f);
        sp[2] = v.z + ((4*g+2 == c) ? EPS_SELF : 0.f);
        sp[3] = v.w + ((4*g+3 == c) ? EPS_SELF : 0.f);
      }
      float ldSp = 0.f;
      gj16(sp, g, c, &ldSp);

      float dmur[4], dmuc;
      {
        float4 a = *(const float4*)(mu_prior + node*16 + 4*g);
        float4 b = *(const float4*)(mu + node*16 + 4*g);
        dmur[0] = a.x - b.x; dmur[1] = a.y - b.y; dmur[2] = a.z - b.z; dmur[3] = a.w - b.w;
        dmuc = mu_prior[node*16 + c] - mu[node*16 + c];
      }
      float4 sv = *(const float4*)(Sigma + node*256 + c*16 + 4*g);
      float val = 0.f;
      {
        float s0 = sv.x + ((4*g+0 == c) ? EPS_SELF : 0.f);
        float s1 = sv.y + ((4*g+1 == c) ? EPS_SELF : 0.f);
        float s2 = sv.z + ((4*g+2 == c) ? EPS_SELF : 0.f);
        float s3 = sv.w + ((4*g+3 == c) ? EPS_SELF : 0.f);
        val = fmaf(sp[0], s0 + dmur[0]*dmuc, val);
        val = fmaf(sp[1], s1 + dmur[1]*dmuc, val);
        val = fmaf(sp[2], s2 + dmur[2]*dmuc, val);
        val = fmaf(sp[3], s3 + dmur[3]*dmuc, val);
      }
      #pragma unroll
      for (int o = 32; o; o >>= 1) val += __shfl_xor(val, o);

      float sq[4];
      sq[0] = sv.x + ((4*g+0 == c) ? EPS_SELF : 0.f);
      sq[1] = sv.y + ((4*g+1 == c) ? EPS_SELF : 0.f);
      sq[2] = sv.z + ((4*g+2 == c) ? EPS_SELF : 0.f);
      sq[3] = sv.w + ((4*g+3 == c) ? EPS_SELF : 0.f);
      float ldSq = ge16_logdet<0>(sq, g, c);
      float sg[4];
      sg[0] = sv.x + ((4*g+0 == c) ? EPS_AL : 0.f);
      sg[1] = sv.y + ((4*g+1 == c) ? EPS_AL : 0.f);
      sg[2] = sv.z + ((4*g+2 == c) ? EPS_AL : 0.f);
      sg[3] = sv.w + ((4*g+3 == c) ? EPS_AL : 0.f);
      float ldq = ge16_logdet<1>(sg, g, c);
      if (l == 0) {
        ws[OFF_KLS + node] = 0.5f * (val - 16.f + ldSp - ldSq);
        ws[OFF_LD + node]  = ldq;
      }
    }
    __syncthreads();   // all prep waves done before release
    if (tid == 0)
      __hip_atomic_fetch_add(prep_cnt, 1u, __ATOMIC_RELEASE, __HIP_MEMORY_SCOPE_AGENT);
    __syncthreads();   // smem safe to reuse for CE
  }

  // ================= Phase C: CE partial sums (all 1024 blocks) =================
  {
    const int grp  = bid & 63;
    const int slot = bid >> 6;           // 0..15
    int v0, v1;
    if (slot < 4)       { v0 = slot*1000;               v1 = v0 + 1000; }
    else if (slot < 8)  { v0 = 4000 + (slot-4)*2500;    v1 = v0 + 2500; }
    else                { v0 = 14000 + (slot-8)*2250;   v1 = v0 + 2250; }
    const int row0 = grp * CE_ROWS;
    float* mu_s = smem;          // 128 floats
    float* wred = smem + 128;    // 32 floats

    if (tid < CE_ROWS*16) mu_s[tid] = mu[row0*16 + tid];
    __syncthreads();

    // Opaque per-lane zero: forces VGPR addressing (no scalar promotion).
    int z = __shfl((int)0, tid);
    const float4* M4 = (const float4*)(mu_s + z);
    float4 Rv[32];
    #pragma unroll
    for (int i = 0; i < 32; ++i) {
      Rv[i] = M4[i];
      asm volatile("" : "+v"(Rv[i].x), "+v"(Rv[i].y), "+v"(Rv[i].z), "+v"(Rv[i].w));
    }

    float acc[CE_ROWS];
    #pragma unroll
    for (int r = 0; r < CE_ROWS; ++r) acc[r] = 0.f;

    const float4* W4 = (const float4*)W;
    for (int v = v0 + tid; v < v1; v += 256) {
      float4 q0 = W4[v*4+0], q1 = W4[v*4+1], q2 = W4[v*4+2], q3 = W4[v*4+3];
      #pragma unroll
      for (int r = 0; r < CE_ROWS; ++r) {
        float lg = dot4(q0, Rv[4*r]) + dot4(q1, Rv[4*r+1])
                 + dot4(q2, Rv[4*r+2]) + dot4(q3, Rv[4*r+3]);
        acc[r] += __expf(lg);   // logits O(0.4): direct exp-sum fp32-safe
      }
    }
    #pragma unroll
    for (int r = 0; r < CE_ROWS; ++r)
      #pragma unroll
      for (int o = 32; o; o >>= 1) acc[r] += __shfl_xor(acc[r], o);
    const int w = tid >> 6, l = tid & 63;
    if (l == 0) {
      #pragma unroll
      for (int r = 0; r < CE_ROWS; ++r) wred[w*CE_ROWS + r] = acc[r];
    }
    __syncthreads();
    if (tid < CE_ROWS)
      ws[OFF_CEP + (row0 + tid)*CE_SLOTS + slot] =
          wred[tid] + wred[CE_ROWS + tid] + wred[2*CE_ROWS + tid] + wred[3*CE_ROWS + tid];
  }
  __syncthreads();

  // ================= Phase A: align (blocks 0..511 only, after prep barrier) =================
  if (bid < 512) {
    if (tid == 0) {
      while (__hip_atomic_load(prep_cnt, __ATOMIC_ACQUIRE, __HIP_MEMORY_SCOPE_AGENT) != 256u)
        __builtin_amdgcn_s_sleep(8);
    }
    __syncthreads();

    const int ti = tid & 15, tj = tid >> 4;
    const int bx = bid & 15, by = (bid >> 4) & 15, bz = bid >> 8;
    const int nodeI0 = bz*256 + by*16, nodeJ0 = bz*256 + bx*16;
    float* OI  = smem;             // 16*260
    float* PJ  = smem + 4160;      // 16*260
    float* mtI = smem + 8320;      // 256
    float* yJ  = smem + 8576;      // 256
    float* wJ  = smem + 8832;      // 16
    float* ldI = smem + 8848;      // 16
    float* ldJ = smem + 8864;      // 16
    float* red = smem + 8880;      // 4

    for (int idx = tid; idx < 16*256; idx += 256) {
      int row = idx >> 8, col = idx & 255;
      OI[row*PSTR + col] = ws[OFF_O + (nodeI0 + row)*256 + col];
      PJ[row*PSTR + col] = ws[OFF_P + (nodeJ0 + row)*256 + col];
    }
    mtI[tid] = ws[OFF_MT + nodeI0*16 + tid];
    yJ[tid]  = ws[OFF_Y  + nodeJ0*16 + tid];
    if (tid < 16) {
      wJ[tid]  = ws[OFF_W  + nodeJ0 + tid];
      ldI[tid] = ws[OFF_LD + nodeI0 + tid];
      ldJ[tid] = ws[OFF_LD + nodeJ0 + tid];
    }
    __syncthreads();

    const float4* oi4 = (const float4*)&OI[ti*PSTR];
    const float4* pj4 = (const float4*)&PJ[tj*PSTR];
    float tr = 0.f;
    #pragma unroll 16
    for (int t = 0; t < 64; ++t) {
      float4 xv = oi4[t], yv = pj4[t];
      tr = fmaf(xv.x, yv.x, tr);
      tr = fmaf(xv.y, yv.y, tr);
      tr = fmaf(xv.z, yv.z, tr);
      tr = fmaf(xv.w, yv.w, tr);
    }
    const float4* mi4 = (const float4*)&mtI[ti*16];
    const float4* yj4 = (const float4*)&yJ[tj*16];
    float diy = dot4(mi4[0], yj4[0]) + dot4(mi4[1], yj4[1])
              + dot4(mi4[2], yj4[2]) + dot4(mi4[3], yj4[3]);

    float kl = 0.5f * (tr + wJ[tj] - 2.f*diy - 16.f + ldJ[tj] - ldI[ti]);
    kl = fmaxf(kl, 0.f);
    int gi = by*16 + ti, gj = bx*16 + tj;
    float contrib = (gi == gj) ? 0.f : kl * beta[bz*65536 + gi*256 + gj];
    #pragma unroll
    for (int o = 32; o; o >>= 1) contrib += __shfl_down(contrib, o);
    __syncthreads();
    if ((tid & 63) == 0) red[tid >> 6] = contrib;
    __syncthreads();
    if (tid == 0)
      ws[OFF_AP + (bz*16 + by)*16 + bx] = red[0] + red[1] + red[2] + red[3];
  }
  __syncthreads();

  // ================= Phase F: completion count; last block does final reduce =================
  if (tid == 0) {
    unsigned old = __hip_atomic_fetch_add(align_cnt, 1u,
                                          __ATOMIC_ACQ_REL, __HIP_MEMORY_SCOPE_AGENT);
    lastflag = (old == 1023u);
  }
  __syncthreads();

  if (lastflag) {
    double* dred = (double*)smem;
    double v[2];
    #pragma unroll
    for (int b = 0; b < 2; ++b) {
      int row = b*256 + tid;
      float s = 0.f;
      #pragma unroll
      for (int c2 = 0; c2 < CE_SLOTS; ++c2) s += ws[OFF_CEP + row*CE_SLOTS + c2];
      int t = targets[row];
      float dt = 0.f;
      const float4* wt4 = (const float4*)(W + t*16);
      const float4* mr4 = (const float4*)(mu + row*16);
      #pragma unroll
      for (int j4 = 0; j4 < 4; ++j4) {
        float4 a = mr4[j4], bb = wt4[j4];
        dt = fmaf(a.x, bb.x, dt); dt = fmaf(a.y, bb.y, dt);
        dt = fmaf(a.z, bb.z, dt); dt = fmaf(a.w, bb.w, dt);
      }
      double ce = (double)logf(s) - (double)dt;
      v[b] = (double)ws[OFF_KLS + row] + (double)ws[OFF_AP + row] + ce;
    }
    for (int b = 0; b < 2; ++b) {
      dred[tid] = v[b];
      __syncthreads();
      for (int h = 128; h > 0; h >>= 1) {
        if (tid < h) dred[tid] += dred[tid + h];
        __syncthreads();
      }
      if (tid == 0) out[b] = (float)dred[0];
      __syncthreads();
    }
  }
}

extern "C" void kernel_launch(void* const* d_in, const int* in_sizes, int n_in,
                              void* d_out, int out_size, void* d_ws, size_t ws_size,
                              hipStream_t stream) {
  const float* mu          = (const float*)d_in[0];
  const float* Sigma       = (const float*)d_in[1];
  const float* phi         = (const float*)d_in[2];
  const float* mu_prior    = (const float*)d_in[3];
  const float* Sigma_prior = (const float*)d_in[4];
  const float* beta        = (const float*)d_in[5];
  const float* W_out       = (const float*)d_in[6];
  const float* gen         = (const float*)d_in[7];
  const int*   targets     = (const int*)d_in[8];
  float* out = (float*)d_out;
  float* ws  = (float*)d_ws;
  if (ws_size < (size_t)WS_FLOATS * sizeof(float)) return;  // fail loudly

  hipMemsetAsync((void*)(ws + OFF_CNT), 0, 2*sizeof(unsigned), stream);
  mega_kernel<<<1024, 256, 0, stream>>>(mu, Sigma, phi, mu_prior, Sigma_prior,
                                        gen, W_out, beta, targets, ws, out);
}

// Round 10
// 59.330 us; speedup vs baseline: 2.6134x; 2.6134x over previous
//
#include <hip/hip_runtime.h>
#include <math.h>

// Sizes fixed by the reference
#define NB 2
#define NN 256
#define KD 16
#define VV 32000
#define EPS_SELF 1e-8f
#define EPS_AL   1e-6f
#define NNODES (NB*NN)   // 512

#define CE_ROWS 4
#define CE_SLOTS 8
// slots 0-1 (prep blocks): 1900 vocab each; slots 2-7: 4700 each.  2*1900+6*4700=32000

// ws layout (float offsets)
#define OFF_MT  0                        // 512*16  rotated means mt
#define OFF_O   (NNODES*16)              // 512*256 O = Shat + mt mt^T
#define OFF_P   (OFF_O + NNODES*256)     // 512*256 P = inv(Shat)
#define OFF_LD  (OFF_P + NNODES*256)     // 512     2*sum log(sqrt(d_k)+eps)
#define OFF_KLS (OFF_LD + NNODES)        // 512     per-node kl_self
#define OFF_AP  (OFF_KLS + NNODES)       // 512     align tile partials
#define OFF_Y   (OFF_AP + NNODES)        // 512*16  y = P mt
#define OFF_W   (OFF_Y + NNODES*16)      // 512     w = mt^T P mt
#define OFF_CEP (OFF_W + NNODES)         // 512*8   ce chunk partial sums
#define OFF_CNT (OFF_CEP + NNODES*CE_SLOTS) // 2 uints: prep_cnt, align_cnt
#define WS_FLOATS (OFF_CNT + 4)

// wave-synchronous LDS visibility (DS pipe in-order per wave): drain lgkm.
#define WAVE_SYNC() asm volatile("s_waitcnt lgkmcnt(0)" ::: "memory")

__device__ __forceinline__ void ld4(float* dst, const float4 v) {
  dst[0] = v.x; dst[1] = v.y; dst[2] = v.z; dst[3] = v.w;
}

__device__ __forceinline__ float dot16a(const float* a, const float* b) {
  float acc = 0.f;
  #pragma unroll
  for (int j = 0; j < 16; ++j) acc = fmaf(a[j], b[j], acc);
  return acc;
}

__device__ __forceinline__ float dot4(float4 a, float4 b) {
  return fmaf(a.x, b.x, fmaf(a.y, b.y, fmaf(a.z, b.z, a.w * b.w)));
}

// In-register Gauss-Jordan inverse of 16x16 via shuffles.
__device__ __forceinline__ void gj16(float aq[4], const int g, const int c, float* ldacc) {
  #pragma unroll
  for (int k = 0; k < 16; ++k) {
    float d    = __shfl(aq[k & 3], ((k >> 2) << 4) | k);
    float rowk = __shfl(aq[k & 3], ((k >> 2) << 4) | c);
    float ck[4];
    #pragma unroll
    for (int q = 0; q < 4; ++q) ck[q] = __shfl(aq[q], (g << 4) | k);
    if (ldacc) *ldacc += logf(d);
    float dinv = 1.f / d;
    #pragma unroll
    for (int q = 0; q < 4; ++q) {
      int r = 4*g + q;
      float vgen = fmaf(-ck[q] * dinv, rowk, aq[q]);
      aq[q] = (r == k) ? ((c == k) ? dinv : aq[q] * dinv)
                       : ((c == k) ? (-ck[q] * dinv) : vgen);
    }
  }
}

template<int QUIRK>
__device__ __forceinline__ float ge16_logdet(float aq[4], const int g, const int c) {
  float ld = 0.f;
  #pragma unroll
  for (int k = 0; k < 16; ++k) {
    float d    = __shfl(aq[k & 3], ((k >> 2) << 4) | k);
    float rowk = __shfl(aq[k & 3], ((k >> 2) << 4) | c);
    float ck[4];
    #pragma unroll
    for (int q = 0; q < 4; ++q) ck[q] = __shfl(aq[q], (g << 4) | k);
    ld += QUIRK ? 2.f * logf(sqrtf(d) + EPS_AL) : logf(d);
    float dinv = 1.f / d;
    #pragma unroll
    for (int q = 0; q < 4; ++q) {
      int r = 4*g + q;
      float upd = fmaf(-ck[q] * dinv, rowk, aq[q]);
      aq[q] = (r > k && c > k) ? upd : aq[q];
    }
  }
  return ld;
}

#define PSTR 260

// ---------------- MEGA kernel, 1024 blocks (4/CU, ALL co-resident) ----------------
// blocks 0..255  (slots 0-1): prep -> CE(1900) -> count -> maybe final
// blocks 256..767(slots 2-5): CE(4700) -> spin on prep -> align tile (bid-256) -> count -> maybe final
// blocks 768..1023(slots 6-7): CE(4700) -> count -> maybe final
__global__ __launch_bounds__(256, 4) void mega_kernel(
    const float* __restrict__ mu, const float* __restrict__ Sigma,
    const float* __restrict__ phi, const float* __restrict__ mu_prior,
    const float* __restrict__ Sigma_prior, const float* __restrict__ gen,
    const float* __restrict__ W, const float* __restrict__ beta,
    const int* __restrict__ targets, float* __restrict__ ws,
    float* __restrict__ out)
{
  __shared__ __align__(16) float smem[8896];   // 35.6 KB, unioned across phases
  __shared__ int lastflag;
  const int tid = threadIdx.x;
  const int bid = blockIdx.x;
  unsigned* prep_cnt  = (unsigned*)(ws + OFF_CNT);
  unsigned* align_cnt = prep_cnt + 1;

  // ================= Phase P: prep (blocks 0..255) =================
  if (bid < 256) {
    const int w = tid >> 6, l = tid & 63;
    const int g = l >> 4, c = l & 15;
    const int unit = bid * 4 + w;
    const int role = unit & 1, node = unit >> 1;
    float* COLp = &smem[w*980];
    float* ROWp = COLp + 320;
    float* AUXp = COLp + 640;

    if (role == 0) {
      float phis[16];
      {
        const float4* p4 = (const float4*)(phi + node*16);
        ld4(phis, p4[0]); ld4(phis+4, p4[1]); ld4(phis+8, p4[2]); ld4(phis+12, p4[3]);
      }
      float x[4] = {0.f, 0.f, 0.f, 0.f};
      #pragma unroll
      for (int aa = 0; aa < 16; ++aa) {
        float4 gq = *(const float4*)(gen + aa*256 + c*16 + 4*g);
        x[0] = fmaf(phis[aa], gq.x, x[0]);
        x[1] = fmaf(phis[aa], gq.y, x[1]);
        x[2] = fmaf(phis[aa], gq.z, x[2]);
        x[3] = fmaf(phis[aa], gq.w, x[3]);
      }
      #pragma unroll
      for (int q = 0; q < 4; ++q) x[q] *= -0.125f;

      #pragma unroll
      for (int q = 0; q < 4; ++q) ROWp[(4*g+q)*20 + c] = x[q];
      WAVE_SYNC();
      float Mrow[4][16];
      #pragma unroll
      for (int q = 0; q < 4; ++q)
        #pragma unroll
        for (int j4 = 0; j4 < 4; ++j4)
          ld4(&Mrow[q][4*j4], *(const float4*)&ROWp[(4*g+q)*20 + 4*j4]);

      float t[4];
      #pragma unroll
      for (int q = 0; q < 4; ++q) t[q] = ((4*g+q) == c ? 1.f : 0.f) + x[q]*0.125f;
      for (int k = 7; k >= 1; --k) {
        *(float4*)&COLp[c*20 + 4*g] = make_float4(t[0], t[1], t[2], t[3]);
        WAVE_SYNC();
        float T[16];
        #pragma unroll
        for (int j4 = 0; j4 < 4; ++j4) ld4(&T[4*j4], *(const float4*)&COLp[c*20 + 4*j4]);
        #pragma unroll
        for (int q = 0; q < 4; ++q)
          t[q] = ((4*g+q) == c ? 1.f : 0.f) + dot16a(Mrow[q], T) / (float)k;
      }
      for (int s = 0; s < 3; ++s) {
        *(float4*)&COLp[c*20 + 4*g] = make_float4(t[0], t[1], t[2], t[3]);
        #pragma unroll
        for (int q = 0; q < 4; ++q) ROWp[(4*g+q)*20 + c] = t[q];
        WAVE_SYNC();
        float T[16];
        #pragma unroll
        for (int j4 = 0; j4 < 4; ++j4) ld4(&T[4*j4], *(const float4*)&COLp[c*20 + 4*j4]);
        float nt[4];
        #pragma unroll
        for (int q = 0; q < 4; ++q) {
          float acc = 0.f;
          #pragma unroll
          for (int j4 = 0; j4 < 4; ++j4) {
            float4 rv = *(const float4*)&ROWp[(4*g+q)*20 + 4*j4];
            acc = fmaf(rv.x, T[4*j4+0], acc);
            acc = fmaf(rv.y, T[4*j4+1], acc);
            acc = fmaf(rv.z, T[4*j4+2], acc);
            acc = fmaf(rv.w, T[4*j4+3], acc);
          }
          nt[q] = acc;
        }
        #pragma unroll
        for (int q = 0; q < 4; ++q) t[q] = nt[q];
      }
      *(float4*)&COLp[c*20 + 4*g] = make_float4(t[0], t[1], t[2], t[3]);
      WAVE_SYNC();
      float Ecol[16];
      #pragma unroll
      for (int j4 = 0; j4 < 4; ++j4) ld4(&Ecol[4*j4], *(const float4*)&COLp[c*20 + 4*j4]);

      float w1q[4];
      #pragma unroll
      for (int q = 0; q < 4; ++q) {
        float S[16];
        const float4* s4 = (const float4*)(Sigma + node*256 + (4*g+q)*16);
        ld4(S, s4[0]); ld4(S+4, s4[1]); ld4(S+8, s4[2]); ld4(S+12, s4[3]);
        w1q[q] = dot16a(S, Ecol);
      }
      *(float4*)&AUXp[c*20 + 4*g] = make_float4(w1q[0], w1q[1], w1q[2], w1q[3]);
      WAVE_SYNC();
      float W1c[16];
      #pragma unroll
      for (int j4 = 0; j4 < 4; ++j4) ld4(&W1c[4*j4], *(const float4*)&AUXp[c*20 + 4*j4]);

      float sh[4];
      #pragma unroll
      for (int q = 0; q < 4; ++q) {
        float Er[16];
        #pragma unroll
        for (int j4 = 0; j4 < 4; ++j4) ld4(&Er[4*j4], *(const float4*)&COLp[(4*g+q)*20 + 4*j4]);
        sh[q] = dot16a(Er, W1c) + ((4*g+q) == c ? EPS_AL : 0.f);
      }

      float mtc;
      {
        float muv[16];
        const float4* m4 = (const float4*)(mu + node*16);
        ld4(muv, m4[0]); ld4(muv+4, m4[1]); ld4(muv+8, m4[2]); ld4(muv+12, m4[3]);
        mtc = dot16a(Ecol, muv);
      }
      float mt4[4];
      #pragma unroll
      for (int q = 0; q < 4; ++q) mt4[q] = __shfl(mtc, 4*g + q);

      *(float4*)(ws + OFF_O + node*256 + c*16 + 4*g) =
          make_float4(fmaf(mt4[0], mtc, sh[0]), fmaf(mt4[1], mtc, sh[1]),
                      fmaf(mt4[2], mtc, sh[2]), fmaf(mt4[3], mtc, sh[3]));
      if (g == 0) ws[OFF_MT + node*16 + c] = mtc;

      gj16(sh, g, c, (float*)nullptr);
      *(float4*)(ws + OFF_P + node*256 + c*16 + 4*g) = make_float4(sh[0], sh[1], sh[2], sh[3]);

      float part = sh[0]*mt4[0] + sh[1]*mt4[1] + sh[2]*mt4[2] + sh[3]*mt4[3];
      part += __shfl_xor(part, 16);
      part += __shfl_xor(part, 32);
      if (g == 0) ws[OFF_Y + node*16 + c] = part;
      float wv = mtc * part;
      wv += __shfl_xor(wv, 1); wv += __shfl_xor(wv, 2);
      wv += __shfl_xor(wv, 4); wv += __shfl_xor(wv, 8);
      if (l == 0) ws[OFF_W + node] = wv;
    } else {
      float sp[4];
      {
        float4 v = *(const float4*)(Sigma_prior + node*256 + c*16 + 4*g);
        sp[0] = v.x + ((4*g+0 == c) ? EPS_SELF : 0.f);
        sp[1] = v.y + ((4*g+1 == c) ? EPS_SELF : 0.f);
        sp[2] = v.z + ((4*g+2 == c) ? EPS_SELF : 0.f);
        sp[3] = v.w + ((4*g+3 == c) ? EPS_SELF : 0.f);
      }
      float ldSp = 0.f;
      gj16(sp, g, c, &ldSp);

      float dmur[4], dmuc;
      {
        float4 a = *(const float4*)(mu_prior + node*16 + 4*g);
        float4 b = *(const float4*)(mu + node*16 + 4*g);
        dmur[0] = a.x - b.x; dmur[1] = a.y - b.y; dmur[2] = a.z - b.z; dmur[3] = a.w - b.w;
        dmuc = mu_prior[node*16 + c] - mu[node*16 + c];
      }
      float4 sv = *(const float4*)(Sigma + node*256 + c*16 + 4*g);
      float val = 0.f;
      {
        float s0 = sv.x + ((4*g+0 == c) ? EPS_SELF : 0.f);
        float s1 = sv.y + ((4*g+1 == c) ? EPS_SELF : 0.f);
        float s2 = sv.z + ((4*g+2 == c) ? EPS_SELF : 0.f);
        float s3 = sv.w + ((4*g+3 == c) ? EPS_SELF : 0.f);
        val = fmaf(sp[0], s0 + dmur[0]*dmuc, val);
        val = fmaf(sp[1], s1 + dmur[1]*dmuc, val);
        val = fmaf(sp[2], s2 + dmur[2]*dmuc, val);
        val = fmaf(sp[3], s3 + dmur[3]*dmuc, val);
      }
      #pragma unroll
      for (int o = 32; o; o >>= 1) val += __shfl_xor(val, o);

      float sq[4];
      sq[0] = sv.x + ((4*g+0 == c) ? EPS_SELF : 0.f);
      sq[1] = sv.y + ((4*g+1 == c) ? EPS_SELF : 0.f);
      sq[2] = sv.z + ((4*g+2 == c) ? EPS_SELF : 0.f);
      sq[3] = sv.w + ((4*g+3 == c) ? EPS_SELF : 0.f);
      float ldSq = ge16_logdet<0>(sq, g, c);
      float sg[4];
      sg[0] = sv.x + ((4*g+0 == c) ? EPS_AL : 0.f);
      sg[1] = sv.y + ((4*g+1 == c) ? EPS_AL : 0.f);
      sg[2] = sv.z + ((4*g+2 == c) ? EPS_AL : 0.f);
      sg[3] = sv.w + ((4*g+3 == c) ? EPS_AL : 0.f);
      float ldq = ge16_logdet<1>(sg, g, c);
      if (l == 0) {
        ws[OFF_KLS + node] = 0.5f * (val - 16.f + ldSp - ldSq);
        ws[OFF_LD + node]  = ldq;
      }
    }
    __syncthreads();   // all prep waves done before release
    if (tid == 0)
      __hip_atomic_fetch_add(prep_cnt, 1u, __ATOMIC_RELEASE, __HIP_MEMORY_SCOPE_AGENT);
    __syncthreads();   // smem safe to reuse for CE
  }

  // ================= Phase C: CE partial sums (all 1024 blocks) =================
  {
    const int grp  = bid & 127;          // 0..127 row group (4 rows each)
    const int slot = bid >> 7;           // 0..7
    int v0, v1;
    if (slot < 2) { v0 = slot*1900;              v1 = v0 + 1900; }
    else          { v0 = 3800 + (slot-2)*4700;   v1 = v0 + 4700; }
    const int row0 = grp * CE_ROWS;
    float* mu_s = smem;          // 64 floats
    float* wred = smem + 64;     // 16 floats

    if (tid < CE_ROWS*16) mu_s[tid] = mu[row0*16 + tid];
    __syncthreads();

    // Opaque per-lane zero: forces VGPR addressing (no scalar promotion).
    int z = __shfl((int)0, tid);
    const float4* M4 = (const float4*)(mu_s + z);
    float4 Rv[16];
    #pragma unroll
    for (int i = 0; i < 16; ++i) {
      Rv[i] = M4[i];
      asm volatile("" : "+v"(Rv[i].x), "+v"(Rv[i].y), "+v"(Rv[i].z), "+v"(Rv[i].w));
    }

    float acc[CE_ROWS];
    #pragma unroll
    for (int r = 0; r < CE_ROWS; ++r) acc[r] = 0.f;

    const float4* W4 = (const float4*)W;
    for (int v = v0 + tid; v < v1; v += 256) {
      float4 q0 = W4[v*4+0], q1 = W4[v*4+1], q2 = W4[v*4+2], q3 = W4[v*4+3];
      #pragma unroll
      for (int r = 0; r < CE_ROWS; ++r) {
        float lg = dot4(q0, Rv[4*r]) + dot4(q1, Rv[4*r+1])
                 + dot4(q2, Rv[4*r+2]) + dot4(q3, Rv[4*r+3]);
        acc[r] += __expf(lg);   // logits O(0.4): direct exp-sum fp32-safe
      }
    }
    #pragma unroll
    for (int r = 0; r < CE_ROWS; ++r)
      #pragma unroll
      for (int o = 32; o; o >>= 1) acc[r] += __shfl_xor(acc[r], o);
    const int w = tid >> 6, l = tid & 63;
    if (l == 0) {
      #pragma unroll
      for (int r = 0; r < CE_ROWS; ++r) wred[w*CE_ROWS + r] = acc[r];
    }
    __syncthreads();
    if (tid < CE_ROWS)
      ws[OFF_CEP + (row0 + tid)*CE_SLOTS + slot] =
          wred[tid] + wred[CE_ROWS + tid] + wred[2*CE_ROWS + tid] + wred[3*CE_ROWS + tid];
  }
  __syncthreads();

  // ================= Phase A: align (blocks 256..767 only) =================
  if (bid >= 256 && bid < 768) {
    if (tid == 0) {
      while (__hip_atomic_load(prep_cnt, __ATOMIC_ACQUIRE, __HIP_MEMORY_SCOPE_AGENT) != 256u)
        __builtin_amdgcn_s_sleep(8);
    }
    __syncthreads();

    const int tile = bid - 256;
    const int ti = tid & 15, tj = tid >> 4;
    const int bx = tile & 15, by = (tile >> 4) & 15, bz = tile >> 8;
    const int nodeI0 = bz*256 + by*16, nodeJ0 = bz*256 + bx*16;
    float* OI  = smem;             // 16*260
    float* PJ  = smem + 4160;      // 16*260
    float* mtI = smem + 8320;      // 256
    float* yJ  = smem + 8576;      // 256
    float* wJ  = smem + 8832;      // 16
    float* ldI = smem + 8848;      // 16
    float* ldJ = smem + 8864;      // 16
    float* red = smem + 8880;      // 4

    for (int idx = tid; idx < 16*256; idx += 256) {
      int row = idx >> 8, col = idx & 255;
      OI[row*PSTR + col] = ws[OFF_O + (nodeI0 + row)*256 + col];
      PJ[row*PSTR + col] = ws[OFF_P + (nodeJ0 + row)*256 + col];
    }
    mtI[tid] = ws[OFF_MT + nodeI0*16 + tid];
    yJ[tid]  = ws[OFF_Y  + nodeJ0*16 + tid];
    if (tid < 16) {
      wJ[tid]  = ws[OFF_W  + nodeJ0 + tid];
      ldI[tid] = ws[OFF_LD + nodeI0 + tid];
      ldJ[tid] = ws[OFF_LD + nodeJ0 + tid];
    }
    __syncthreads();

    const float4* oi4 = (const float4*)&OI[ti*PSTR];
    const float4* pj4 = (const float4*)&PJ[tj*PSTR];
    float tr = 0.f;
    #pragma unroll 16
    for (int t = 0; t < 64; ++t) {
      float4 xv = oi4[t], yv = pj4[t];
      tr = fmaf(xv.x, yv.x, tr);
      tr = fmaf(xv.y, yv.y, tr);
      tr = fmaf(xv.z, yv.z, tr);
      tr = fmaf(xv.w, yv.w, tr);
    }
    const float4* mi4 = (const float4*)&mtI[ti*16];
    const float4* yj4 = (const float4*)&yJ[tj*16];
    float diy = dot4(mi4[0], yj4[0]) + dot4(mi4[1], yj4[1])
              + dot4(mi4[2], yj4[2]) + dot4(mi4[3], yj4[3]);

    float kl = 0.5f * (tr + wJ[tj] - 2.f*diy - 16.f + ldJ[tj] - ldI[ti]);
    kl = fmaxf(kl, 0.f);
    int gi = by*16 + ti, gj = bx*16 + tj;
    float contrib = (gi == gj) ? 0.f : kl * beta[bz*65536 + gi*256 + gj];
    #pragma unroll
    for (int o = 32; o; o >>= 1) contrib += __shfl_down(contrib, o);
    __syncthreads();
    if ((tid & 63) == 0) red[tid >> 6] = contrib;
    __syncthreads();
    if (tid == 0)
      ws[OFF_AP + (bz*16 + by)*16 + bx] = red[0] + red[1] + red[2] + red[3];
  }
  __syncthreads();

  // ================= Phase F: completion count; last block does final reduce =================
  if (tid == 0) {
    unsigned old = __hip_atomic_fetch_add(align_cnt, 1u,
                                          __ATOMIC_ACQ_REL, __HIP_MEMORY_SCOPE_AGENT);
    lastflag = (old == 1023u);
  }
  __syncthreads();

  if (lastflag) {
    double* dred = (double*)smem;
    double v[2];
    #pragma unroll
    for (int b = 0; b < 2; ++b) {
      int row = b*256 + tid;
      float s = 0.f;
      #pragma unroll
      for (int c2 = 0; c2 < CE_SLOTS; ++c2) s += ws[OFF_CEP + row*CE_SLOTS + c2];
      int t = targets[row];
      float dt = 0.f;
      const float4* wt4 = (const float4*)(W + t*16);
      const float4* mr4 = (const float4*)(mu + row*16);
      #pragma unroll
      for (int j4 = 0; j4 < 4; ++j4) {
        float4 a = mr4[j4], bb = wt4[j4];
        dt = fmaf(a.x, bb.x, dt); dt = fmaf(a.y, bb.y, dt);
        dt = fmaf(a.z, bb.z, dt); dt = fmaf(a.w, bb.w, dt);
      }
      double ce = (double)logf(s) - (double)dt;
      v[b] = (double)ws[OFF_KLS + row] + (double)ws[OFF_AP + row] + ce;
    }
    for (int b = 0; b < 2; ++b) {
      dred[tid] = v[b];
      __syncthreads();
      for (int h = 128; h > 0; h >>= 1) {
        if (tid < h) dred[tid] += dred[tid + h];
        __syncthreads();
      }
      if (tid == 0) out[b] = (float)dred[0];
      __syncthreads();
    }
  }
}

extern "C" void kernel_launch(void* const* d_in, const int* in_sizes, int n_in,
                              void* d_out, int out_size, void* d_ws, size_t ws_size,
                              hipStream_t stream) {
  const float* mu          = (const float*)d_in[0];
  const float* Sigma       = (const float*)d_in[1];
  const float* phi         = (const float*)d_in[2];
  const float* mu_prior    = (const float*)d_in[3];
  const float* Sigma_prior = (const float*)d_in[4];
  const float* beta        = (const float*)d_in[5];
  const float* W_out       = (const float*)d_in[6];
  const float* gen         = (const float*)d_in[7];
  const int*   targets     = (const int*)d_in[8];
  float* out = (float*)d_out;
  float* ws  = (float*)d_ws;
  if (ws_size < (size_t)WS_FLOATS * sizeof(float)) return;  // fail loudly

  hipMemsetAsync((void*)(ws + OFF_CNT), 0, 2*sizeof(unsigned), stream);
  mega_kernel<<<1024, 256, 0, stream>>>(mu, Sigma, phi, mu_prior, Sigma_prior,
                                        gen, W_out, beta, targets, ws, out);
}

// Round 11
// 46.114 us; speedup vs baseline: 3.3624x; 1.2866x over previous
//
#include <hip/hip_runtime.h>
#include <math.h>

// Sizes fixed by the reference
#define NB 2
#define NN 256
#define KD 16
#define VV 32000
#define EPS_SELF 1e-8f
#define EPS_AL   1e-6f
#define NNODES (NB*NN)   // 512

#define CE_ROWS 4
#define CE_SLOTS 32
#define CE_CHUNK 1000    // 32*1000 = 32000
#define CE_BLOCKS (128*CE_SLOTS)   // 4096

// ws layout (float offsets)
#define OFF_MT  0                        // 512*16  rotated means mt
#define OFF_O   (NNODES*16)              // 512*256 O = Shat + mt mt^T
#define OFF_P   (OFF_O + NNODES*256)     // 512*256 P = inv(Shat)
#define OFF_LD  (OFF_P + NNODES*256)     // 512     2*sum log(sqrt(d_k)+eps)
#define OFF_KLS (OFF_LD + NNODES)        // 512     per-node kl_self
#define OFF_AP  (OFF_KLS + NNODES)       // 512     align tile partials
#define OFF_Y   (OFF_AP + NNODES)        // 512*16  y = P mt
#define OFF_W   (OFF_Y + NNODES*16)      // 512     w = mt^T P mt
#define OFF_CEP (OFF_W + NNODES)         // 512*32  ce chunk partial sums
#define OFF_CNT (OFF_CEP + NNODES*CE_SLOTS) // 1 uint: B's completion counter
#define WS_FLOATS (OFF_CNT + 4)

// wave-synchronous LDS visibility (DS pipe in-order per wave): drain lgkm.
#define WAVE_SYNC() asm volatile("s_waitcnt lgkmcnt(0)" ::: "memory")

__device__ __forceinline__ void ld4(float* dst, const float4 v) {
  dst[0] = v.x; dst[1] = v.y; dst[2] = v.z; dst[3] = v.w;
}

__device__ __forceinline__ float dot16a(const float* a, const float* b) {
  float acc = 0.f;
  #pragma unroll
  for (int j = 0; j < 16; ++j) acc = fmaf(a[j], b[j], acc);
  return acc;
}

__device__ __forceinline__ float dot4(float4 a, float4 b) {
  return fmaf(a.x, b.x, fmaf(a.y, b.y, fmaf(a.z, b.z, a.w * b.w)));
}

// In-register Gauss-Jordan inverse of 16x16 via shuffles.
__device__ __forceinline__ void gj16(float aq[4], const int g, const int c, float* ldacc) {
  #pragma unroll
  for (int k = 0; k < 16; ++k) {
    float d    = __shfl(aq[k & 3], ((k >> 2) << 4) | k);
    float rowk = __shfl(aq[k & 3], ((k >> 2) << 4) | c);
    float ck[4];
    #pragma unroll
    for (int q = 0; q < 4; ++q) ck[q] = __shfl(aq[q], (g << 4) | k);
    if (ldacc) *ldacc += logf(d);
    float dinv = 1.f / d;
    #pragma unroll
    for (int q = 0; q < 4; ++q) {
      int r = 4*g + q;
      float vgen = fmaf(-ck[q] * dinv, rowk, aq[q]);
      aq[q] = (r == k) ? ((c == k) ? dinv : aq[q] * dinv)
                       : ((c == k) ? (-ck[q] * dinv) : vgen);
    }
  }
}

template<int QUIRK>
__device__ __forceinline__ float ge16_logdet(float aq[4], const int g, const int c) {
  float ld = 0.f;
  #pragma unroll
  for (int k = 0; k < 16; ++k) {
    float d    = __shfl(aq[k & 3], ((k >> 2) << 4) | k);
    float rowk = __shfl(aq[k & 3], ((k >> 2) << 4) | c);
    float ck[4];
    #pragma unroll
    for (int q = 0; q < 4; ++q) ck[q] = __shfl(aq[q], (g << 4) | k);
    ld += QUIRK ? 2.f * logf(sqrtf(d) + EPS_AL) : logf(d);
    float dinv = 1.f / d;
    #pragma unroll
    for (int q = 0; q < 4; ++q) {
      int r = 4*g + q;
      float upd = fmaf(-ck[q] * dinv, rowk, aq[q]);
      aq[q] = (r > k && c > k) ? upd : aq[q];
    }
  }
  return ld;
}

// ---------------- Kernel A: prep (blocks 0..255) UNION CE (blocks 256..4351) ----------------
__global__ __launch_bounds__(256, 4) void kernelA(
    const float* __restrict__ mu, const float* __restrict__ Sigma,
    const float* __restrict__ phi, const float* __restrict__ mu_prior,
    const float* __restrict__ Sigma_prior, const float* __restrict__ gen,
    const float* __restrict__ W, float* __restrict__ ws)
{
  __shared__ __align__(16) float smem[4][980];
  const int tid = threadIdx.x;
  const int bid = blockIdx.x;

  if (bid < 256) {
    if (bid == 0 && tid == 0) *(unsigned*)(ws + OFF_CNT) = 0u;  // reset B's counter
    const int w = tid >> 6, l = tid & 63;
    const int g = l >> 4, c = l & 15;
    const int unit = bid * 4 + w;
    const int role = unit & 1, node = unit >> 1;
    float* COLp = &smem[w][0];
    float* ROWp = COLp + 320;
    float* AUXp = COLp + 640;

    if (role == 0) {
      float phis[16];
      {
        const float4* p4 = (const float4*)(phi + node*16);
        ld4(phis, p4[0]); ld4(phis+4, p4[1]); ld4(phis+8, p4[2]); ld4(phis+12, p4[3]);
      }
      // X[4g+q][c] = -0.125*sum_a phi_a gen[a][c][4g+q]  (gen exactly skew)
      float x[4] = {0.f, 0.f, 0.f, 0.f};
      #pragma unroll
      for (int aa = 0; aa < 16; ++aa) {
        float4 gq = *(const float4*)(gen + aa*256 + c*16 + 4*g);
        x[0] = fmaf(phis[aa], gq.x, x[0]);
        x[1] = fmaf(phis[aa], gq.y, x[1]);
        x[2] = fmaf(phis[aa], gq.z, x[2]);
        x[3] = fmaf(phis[aa], gq.w, x[3]);
      }
      #pragma unroll
      for (int q = 0; q < 4; ++q) x[q] *= -0.125f;

      #pragma unroll
      for (int q = 0; q < 4; ++q) ROWp[(4*g+q)*20 + c] = x[q];
      WAVE_SYNC();
      float Mrow[4][16];
      #pragma unroll
      for (int q = 0; q < 4; ++q)
        #pragma unroll
        for (int j4 = 0; j4 < 4; ++j4)
          ld4(&Mrow[q][4*j4], *(const float4*)&ROWp[(4*g+q)*20 + 4*j4]);

      // Horner order 8
      float t[4];
      #pragma unroll
      for (int q = 0; q < 4; ++q) t[q] = ((4*g+q) == c ? 1.f : 0.f) + x[q]*0.125f;
      for (int k = 7; k >= 1; --k) {
        *(float4*)&COLp[c*20 + 4*g] = make_float4(t[0], t[1], t[2], t[3]);
        WAVE_SYNC();
        float T[16];
        #pragma unroll
        for (int j4 = 0; j4 < 4; ++j4) ld4(&T[4*j4], *(const float4*)&COLp[c*20 + 4*j4]);
        #pragma unroll
        for (int q = 0; q < 4; ++q)
          t[q] = ((4*g+q) == c ? 1.f : 0.f) + dot16a(Mrow[q], T) / (float)k;
      }
      // 3 squarings -> E (orthogonal)
      for (int s = 0; s < 3; ++s) {
        *(float4*)&COLp[c*20 + 4*g] = make_float4(t[0], t[1], t[2], t[3]);
        #pragma unroll
        for (int q = 0; q < 4; ++q) ROWp[(4*g+q)*20 + c] = t[q];
        WAVE_SYNC();
        float T[16];
        #pragma unroll
        for (int j4 = 0; j4 < 4; ++j4) ld4(&T[4*j4], *(const float4*)&COLp[c*20 + 4*j4]);
        float nt[4];
        #pragma unroll
        for (int q = 0; q < 4; ++q) {
          float acc = 0.f;
          #pragma unroll
          for (int j4 = 0; j4 < 4; ++j4) {
            float4 rv = *(const float4*)&ROWp[(4*g+q)*20 + 4*j4];
            acc = fmaf(rv.x, T[4*j4+0], acc);
            acc = fmaf(rv.y, T[4*j4+1], acc);
            acc = fmaf(rv.z, T[4*j4+2], acc);
            acc = fmaf(rv.w, T[4*j4+3], acc);
          }
          nt[q] = acc;
        }
        #pragma unroll
        for (int q = 0; q < 4; ++q) t[q] = nt[q];
      }
      *(float4*)&COLp[c*20 + 4*g] = make_float4(t[0], t[1], t[2], t[3]);
      WAVE_SYNC();
      float Ecol[16];
      #pragma unroll
      for (int j4 = 0; j4 < 4; ++j4) ld4(&Ecol[4*j4], *(const float4*)&COLp[c*20 + 4*j4]);

      float w1q[4];
      #pragma unroll
      for (int q = 0; q < 4; ++q) {
        float S[16];
        const float4* s4 = (const float4*)(Sigma + node*256 + (4*g+q)*16);
        ld4(S, s4[0]); ld4(S+4, s4[1]); ld4(S+8, s4[2]); ld4(S+12, s4[3]);
        w1q[q] = dot16a(S, Ecol);
      }
      *(float4*)&AUXp[c*20 + 4*g] = make_float4(w1q[0], w1q[1], w1q[2], w1q[3]);
      WAVE_SYNC();
      float W1c[16];
      #pragma unroll
      for (int j4 = 0; j4 < 4; ++j4) ld4(&W1c[4*j4], *(const float4*)&AUXp[c*20 + 4*j4]);

      float sh[4];
      #pragma unroll
      for (int q = 0; q < 4; ++q) {
        float Er[16];
        #pragma unroll
        for (int j4 = 0; j4 < 4; ++j4) ld4(&Er[4*j4], *(const float4*)&COLp[(4*g+q)*20 + 4*j4]);
        sh[q] = dot16a(Er, W1c) + ((4*g+q) == c ? EPS_AL : 0.f);
      }

      float mtc;
      {
        float muv[16];
        const float4* m4 = (const float4*)(mu + node*16);
        ld4(muv, m4[0]); ld4(muv+4, m4[1]); ld4(muv+8, m4[2]); ld4(muv+12, m4[3]);
        mtc = dot16a(Ecol, muv);
      }
      float mt4[4];
      #pragma unroll
      for (int q = 0; q < 4; ++q) mt4[q] = __shfl(mtc, 4*g + q);

      *(float4*)(ws + OFF_O + node*256 + c*16 + 4*g) =
          make_float4(fmaf(mt4[0], mtc, sh[0]), fmaf(mt4[1], mtc, sh[1]),
                      fmaf(mt4[2], mtc, sh[2]), fmaf(mt4[3], mtc, sh[3]));
      if (g == 0) ws[OFF_MT + node*16 + c] = mtc;

      gj16(sh, g, c, (float*)nullptr);
      *(float4*)(ws + OFF_P + node*256 + c*16 + 4*g) = make_float4(sh[0], sh[1], sh[2], sh[3]);

      float part = sh[0]*mt4[0] + sh[1]*mt4[1] + sh[2]*mt4[2] + sh[3]*mt4[3];
      part += __shfl_xor(part, 16);
      part += __shfl_xor(part, 32);
      if (g == 0) ws[OFF_Y + node*16 + c] = part;
      float wv = mtc * part;
      wv += __shfl_xor(wv, 1); wv += __shfl_xor(wv, 2);
      wv += __shfl_xor(wv, 4); wv += __shfl_xor(wv, 8);
      if (l == 0) ws[OFF_W + node] = wv;
    } else {
      float sp[4];
      {
        float4 v = *(const float4*)(Sigma_prior + node*256 + c*16 + 4*g);
        sp[0] = v.x + ((4*g+0 == c) ? EPS_SELF : 0.f);
        sp[1] = v.y + ((4*g+1 == c) ? EPS_SELF : 0.f);
        sp[2] = v.z + ((4*g+2 == c) ? EPS_SELF : 0.f);
        sp[3] = v.w + ((4*g+3 == c) ? EPS_SELF : 0.f);
      }
      float ldSp = 0.f;
      gj16(sp, g, c, &ldSp);

      float dmur[4], dmuc;
      {
        float4 a = *(const float4*)(mu_prior + node*16 + 4*g);
        float4 b = *(const float4*)(mu + node*16 + 4*g);
        dmur[0] = a.x - b.x; dmur[1] = a.y - b.y; dmur[2] = a.z - b.z; dmur[3] = a.w - b.w;
        dmuc = mu_prior[node*16 + c] - mu[node*16 + c];
      }
      float4 sv = *(const float4*)(Sigma + node*256 + c*16 + 4*g);
      float val = 0.f;
      {
        float s0 = sv.x + ((4*g+0 == c) ? EPS_SELF : 0.f);
        float s1 = sv.y + ((4*g+1 == c) ? EPS_SELF : 0.f);
        float s2 = sv.z + ((4*g+2 == c) ? EPS_SELF : 0.f);
        float s3 = sv.w + ((4*g+3 == c) ? EPS_SELF : 0.f);
        val = fmaf(sp[0], s0 + dmur[0]*dmuc, val);
        val = fmaf(sp[1], s1 + dmur[1]*dmuc, val);
        val = fmaf(sp[2], s2 + dmur[2]*dmuc, val);
        val = fmaf(sp[3], s3 + dmur[3]*dmuc, val);
      }
      #pragma unroll
      for (int o = 32; o; o >>= 1) val += __shfl_xor(val, o);

      float sq[4];
      sq[0] = sv.x + ((4*g+0 == c) ? EPS_SELF : 0.f);
      sq[1] = sv.y + ((4*g+1 == c) ? EPS_SELF : 0.f);
      sq[2] = sv.z + ((4*g+2 == c) ? EPS_SELF : 0.f);
      sq[3] = sv.w + ((4*g+3 == c) ? EPS_SELF : 0.f);
      float ldSq = ge16_logdet<0>(sq, g, c);
      float sg[4];
      sg[0] = sv.x + ((4*g+0 == c) ? EPS_AL : 0.f);
      sg[1] = sv.y + ((4*g+1 == c) ? EPS_AL : 0.f);
      sg[2] = sv.z + ((4*g+2 == c) ? EPS_AL : 0.f);
      sg[3] = sv.w + ((4*g+3 == c) ? EPS_AL : 0.f);
      float ldq = ge16_logdet<1>(sg, g, c);
      if (l == 0) {
        ws[OFF_KLS + node] = 0.5f * (val - 16.f + ldSp - ldSq);
        ws[OFF_LD + node]  = ldq;
      }
    }
  } else {
    // ---------- CE: 4096 blocks, 128 row-groups x 32 chunks of 1000 ----------
    const int idx  = bid - 256;
    const int grp  = idx & 127;          // row group (4 rows)
    const int slot = idx >> 7;           // 0..31
    const int v0 = slot * CE_CHUNK, v1 = v0 + CE_CHUNK;
    const int row0 = grp * CE_ROWS;
    float* mu_s = &smem[0][0];   // 64 floats
    float* wred = &smem[0][64];  // 16 floats

    if (tid < CE_ROWS*16) mu_s[tid] = mu[row0*16 + tid];
    __syncthreads();

    // Opaque per-lane zero: forces VGPR addressing (no scalar promotion).
    int z = __shfl((int)0, tid);
    const float4* M4 = (const float4*)(mu_s + z);
    float4 Rv[16];
    #pragma unroll
    for (int i = 0; i < 16; ++i) {
      Rv[i] = M4[i];
      asm volatile("" : "+v"(Rv[i].x), "+v"(Rv[i].y), "+v"(Rv[i].z), "+v"(Rv[i].w));
    }

    float acc[CE_ROWS];
    #pragma unroll
    for (int r = 0; r < CE_ROWS; ++r) acc[r] = 0.f;

    const float4* W4 = (const float4*)W;
    for (int v = v0 + tid; v < v1; v += 256) {
      float4 q0 = W4[v*4+0], q1 = W4[v*4+1], q2 = W4[v*4+2], q3 = W4[v*4+3];
      #pragma unroll
      for (int r = 0; r < CE_ROWS; ++r) {
        float lg = dot4(q0, Rv[4*r]) + dot4(q1, Rv[4*r+1])
                 + dot4(q2, Rv[4*r+2]) + dot4(q3, Rv[4*r+3]);
        acc[r] += __expf(lg);   // logits O(0.4): direct exp-sum fp32-safe
      }
    }
    #pragma unroll
    for (int r = 0; r < CE_ROWS; ++r)
      #pragma unroll
      for (int o = 32; o; o >>= 1) acc[r] += __shfl_xor(acc[r], o);
    const int w = tid >> 6, l = tid & 63;
    if (l == 0) {
      #pragma unroll
      for (int r = 0; r < CE_ROWS; ++r) wred[w*CE_ROWS + r] = acc[r];
    }
    __syncthreads();
    if (tid < CE_ROWS)
      ws[OFF_CEP + (row0 + tid)*CE_SLOTS + slot] =
          wred[tid] + wred[CE_ROWS + tid] + wred[2*CE_ROWS + tid] + wred[3*CE_ROWS + tid];
  }
}

// ---------------- Kernel B: pairwise V_align + last-block final reduce ----------------
#define PSTR 260
__global__ __launch_bounds__(256, 2) void kernelB(
    const float* __restrict__ beta, const float* __restrict__ mu,
    const float* __restrict__ W, const int* __restrict__ targets,
    float* __restrict__ ws, float* __restrict__ out)
{
  __shared__ __align__(16) float OI[16*PSTR];
  __shared__ __align__(16) float PJ[16*PSTR];
  __shared__ __align__(16) float mtI[256];
  __shared__ __align__(16) float yJ[256];
  __shared__ float wJ[16], ldI[16], ldJ[16], red[4];
  __shared__ int lastflag;
  const int tid = threadIdx.x;
  const int ti = tid & 15, tj = tid >> 4;
  const int bx = blockIdx.x & 15, by = (blockIdx.x >> 4) & 15, bz = blockIdx.x >> 8;
  const int nodeI0 = bz*256 + by*16, nodeJ0 = bz*256 + bx*16;

  // float4 staging: 1024 quads over 256 threads = 4 x global_load_dwordx4 each
  {
    const float4* src_o = (const float4*)(ws + OFF_O + nodeI0*256);
    const float4* src_p = (const float4*)(ws + OFF_P + nodeJ0*256);
    float4* dst_o = (float4*)OI;
    float4* dst_p = (float4*)PJ;
    #pragma unroll
    for (int q = tid; q < 1024; q += 256) {
      int row = q >> 6, c4 = q & 63;
      dst_o[row*65 + c4] = src_o[q];
      dst_p[row*65 + c4] = src_p[q];
    }
  }
  mtI[tid] = ws[OFF_MT + nodeI0*16 + tid];
  yJ[tid]  = ws[OFF_Y  + nodeJ0*16 + tid];
  if (tid < 16) {
    wJ[tid]  = ws[OFF_W  + nodeJ0 + tid];
    ldI[tid] = ws[OFF_LD + nodeI0 + tid];
    ldJ[tid] = ws[OFF_LD + nodeJ0 + tid];
  }
  __syncthreads();

  const float4* oi4 = (const float4*)&OI[ti*PSTR];
  const float4* pj4 = (const float4*)&PJ[tj*PSTR];
  float tr = 0.f;
  #pragma unroll 16
  for (int t = 0; t < 64; ++t) {
    float4 xv = oi4[t], yv = pj4[t];
    tr = fmaf(xv.x, yv.x, tr);
    tr = fmaf(xv.y, yv.y, tr);
    tr = fmaf(xv.z, yv.z, tr);
    tr = fmaf(xv.w, yv.w, tr);
  }
  const float4* mi4 = (const float4*)&mtI[ti*16];
  const float4* yj4 = (const float4*)&yJ[tj*16];
  float diy = dot4(mi4[0], yj4[0]) + dot4(mi4[1], yj4[1])
            + dot4(mi4[2], yj4[2]) + dot4(mi4[3], yj4[3]);

  float kl = 0.5f * (tr + wJ[tj] - 2.f*diy - 16.f + ldJ[tj] - ldI[ti]);
  kl = fmaxf(kl, 0.f);
  int gi = by*16 + ti, gj = bx*16 + tj;
  float contrib = (gi == gj) ? 0.f : kl * beta[bz*65536 + gi*256 + gj];
  #pragma unroll
  for (int o = 32; o; o >>= 1) contrib += __shfl_down(contrib, o);
  __syncthreads();
  if ((tid & 63) == 0) red[tid >> 6] = contrib;
  __syncthreads();
  if (tid == 0) {
    ws[OFF_AP + (bz*16 + by)*16 + bx] = red[0] + red[1] + red[2] + red[3];
    unsigned old = __hip_atomic_fetch_add((unsigned*)(ws + OFF_CNT), 1u,
                                          __ATOMIC_ACQ_REL, __HIP_MEMORY_SCOPE_AGENT);
    lastflag = (old == 511u);
  }
  __syncthreads();

  if (lastflag) {
    // deterministic final reduce: fixed order, independent of which block is last
    double* dred = (double*)OI;   // reuse LDS
    double v[2];
    #pragma unroll
    for (int b = 0; b < 2; ++b) {
      int row = b*256 + tid;
      float s = 0.f;
      #pragma unroll
      for (int c2 = 0; c2 < CE_SLOTS; ++c2) s += ws[OFF_CEP + row*CE_SLOTS + c2];
      int t = targets[row];
      float dt = 0.f;
      const float4* wt4 = (const float4*)(W + t*16);
      const float4* mr4 = (const float4*)(mu + row*16);
      #pragma unroll
      for (int j4 = 0; j4 < 4; ++j4) {
        float4 a = mr4[j4], bb = wt4[j4];
        dt = fmaf(a.x, bb.x, dt); dt = fmaf(a.y, bb.y, dt);
        dt = fmaf(a.z, bb.z, dt); dt = fmaf(a.w, bb.w, dt);
      }
      double ce = (double)logf(s) - (double)dt;
      v[b] = (double)ws[OFF_KLS + row] + (double)ws[OFF_AP + row] + ce;
    }
    for (int b = 0; b < 2; ++b) {
      dred[tid] = v[b];
      __syncthreads();
      for (int h = 128; h > 0; h >>= 1) {
        if (tid < h) dred[tid] += dred[tid + h];
        __syncthreads();
      }
      if (tid == 0) out[b] = (float)dred[0];
      __syncthreads();
    }
  }
}

extern "C" void kernel_launch(void* const* d_in, const int* in_sizes, int n_in,
                              void* d_out, int out_size, void* d_ws, size_t ws_size,
                              hipStream_t stream) {
  const float* mu          = (const float*)d_in[0];
  const float* Sigma       = (const float*)d_in[1];
  const float* phi         = (const float*)d_in[2];
  const float* mu_prior    = (const float*)d_in[3];
  const float* Sigma_prior = (const float*)d_in[4];
  const float* beta        = (const float*)d_in[5];
  const float* W_out       = (const float*)d_in[6];
  const float* gen         = (const float*)d_in[7];
  const int*   targets     = (const int*)d_in[8];
  float* out = (float*)d_out;
  float* ws  = (float*)d_ws;
  if (ws_size < (size_t)WS_FLOATS * sizeof(float)) return;  // fail loudly

  kernelA<<<256 + CE_BLOCKS, 256, 0, stream>>>(
      mu, Sigma, phi, mu_prior, Sigma_prior, gen, W_out, ws);
  kernelB<<<NB*16*16, 256, 0, stream>>>(beta, mu, W_out, targets, ws, out);
}